// Round 1
// baseline (199.313 us; speedup 1.0000x reference)
//
#include <hip/hip_runtime.h>
#include <math.h>

#define D 768
#define NPROTO 20
#define NCLS 13

// ws layout (floats): [0, 15360) protos_norm [20][768]; [15360, 15620) logits [20][13]

__global__ __launch_bounds__(256) void proto_prep(
    const float* __restrict__ prototypes,
    const int* __restrict__ role_id,
    const float* __restrict__ W,
    const float* __restrict__ bvec,
    float* __restrict__ ws)
{
    const int tid = threadIdx.x;
    const int wave = tid >> 6;
    const int lane = tid & 63;
    const float* base = prototypes + (size_t)role_id[0] * NPROTO * D;
    float* pn = ws;                 // [NPROTO][D]
    float* lg = ws + NPROTO * D;    // [NPROTO][NCLS]

    for (int p = wave; p < NPROTO; p += 4) {
        const float4* src = reinterpret_cast<const float4*>(base + (size_t)p * D);
        float4 v[3];
        #pragma unroll
        for (int j = 0; j < 3; ++j) v[j] = src[lane + 64 * j];

        float ss = 0.f;
        #pragma unroll
        for (int j = 0; j < 3; ++j)
            ss += v[j].x * v[j].x + v[j].y * v[j].y + v[j].z * v[j].z + v[j].w * v[j].w;
        #pragma unroll
        for (int s = 1; s < 64; s <<= 1) ss += __shfl_xor(ss, s, 64);
        const float nrm = fmaxf(sqrtf(ss), 1e-12f);

        float4 nv[3];
        float4* dst = reinterpret_cast<float4*>(pn + (size_t)p * D);
        #pragma unroll
        for (int j = 0; j < 3; ++j) {
            float4 n;
            n.x = v[j].x / nrm; n.y = v[j].y / nrm;
            n.z = v[j].z / nrm; n.w = v[j].w / nrm;
            dst[lane + 64 * j] = n;
            nv[j] = n;
        }

        // logits[p][r] = dot(protos_norm[p], W[r]) + b[r]
        float acc[NCLS];
        #pragma unroll
        for (int r = 0; r < NCLS; ++r) {
            const float4* wr = reinterpret_cast<const float4*>(W + (size_t)r * D);
            float a = 0.f;
            #pragma unroll
            for (int j = 0; j < 3; ++j) {
                const float4 wv = wr[lane + 64 * j];
                a += nv[j].x * wv.x + nv[j].y * wv.y + nv[j].z * wv.z + nv[j].w * wv.w;
            }
            acc[r] = a;
        }
        #pragma unroll
        for (int r = 0; r < NCLS; ++r) {
            #pragma unroll
            for (int s = 1; s < 64; s <<= 1) acc[r] += __shfl_xor(acc[r], s, 64);
        }
        if (lane == 0) {
            #pragma unroll
            for (int r = 0; r < NCLS; ++r) lg[p * NCLS + r] = acc[r] + bvec[r];
        }
    }
}

// 16 lanes per row, 4 rows per wave per iteration, 4 iterations -> 64 rows/block
__global__ __launch_bounds__(256, 2) void proto_main(
    const float* __restrict__ x,
    const float* __restrict__ ws,
    float* __restrict__ out_min,
    float* __restrict__ out_pred)
{
    __shared__ float pl[NPROTO * D];        // 61440 B
    __shared__ float lgs[NPROTO * NCLS];    // 1040 B
    const int tid = threadIdx.x;

    // stage protos_norm + logits into LDS
    {
        const float4* src = reinterpret_cast<const float4*>(ws);
        float4* dst = reinterpret_cast<float4*>(pl);
        #pragma unroll
        for (int k = 0; k < 15; ++k) dst[tid + 256 * k] = src[tid + 256 * k];
        lgs[tid] = ws[NPROTO * D + tid];
        if (tid < NPROTO * NCLS - 256) lgs[256 + tid] = ws[NPROTO * D + 256 + tid];
    }
    __syncthreads();

    const int wave = tid >> 6;
    const int lane = tid & 63;
    const int g = lane >> 4;        // which of 4 rows this lane works on
    const int sub = lane & 15;      // position within the 16-lane row group
    const int row0 = blockIdx.x * 64 + wave * 4 + g;

    float4 xc[12], xn[12];
    {
        const float4* xr = reinterpret_cast<const float4*>(x + (size_t)row0 * D);
        #pragma unroll
        for (int j = 0; j < 12; ++j) xc[j] = xr[sub + 16 * j];
    }

    #pragma unroll
    for (int it = 0; it < 4; ++it) {
        const int row = row0 + it * 16;
        if (it < 3) {   // prefetch next row group while computing current
            const float4* xr = reinterpret_cast<const float4*>(x + (size_t)(row + 16) * D);
            #pragma unroll
            for (int j = 0; j < 12; ++j) xn[j] = xr[sub + 16 * j];
        }

        float acc[NPROTO];
        #pragma unroll
        for (int p = 0; p < NPROTO; ++p) acc[p] = 0.f;
        float ssx = 0.f;

        #pragma unroll
        for (int j = 0; j < 12; ++j) {
            const float4 xv = xc[j];
            ssx += xv.x * xv.x + xv.y * xv.y + xv.z * xv.z + xv.w * xv.w;
            const float4* pr = reinterpret_cast<const float4*>(pl) + sub + 16 * j;
            #pragma unroll
            for (int p = 0; p < NPROTO; ++p) {
                const float4 pv = pr[p * (D / 4)];
                acc[p] += xv.x * pv.x + xv.y * pv.y + xv.z * pv.z + xv.w * pv.w;
            }
        }

        // reduce across the 16-lane row group (xor 1,2,4,8 stays in group)
        #pragma unroll
        for (int s = 1; s < 16; s <<= 1) ssx += __shfl_xor(ssx, s, 64);
        #pragma unroll
        for (int p = 0; p < NPROTO; ++p) {
            #pragma unroll
            for (int s = 1; s < 16; s <<= 1) acc[p] += __shfl_xor(acc[p], s, 64);
        }

        const float inv = 1.0f / fmaxf(sqrtf(ssx), 1e-12f);

        // np-order scan in dist space (strict > keeps first index on ties)
        float best = 0.f; int bidx = 0;
        #pragma unroll
        for (int p = 0; p < NPROTO; ++p) {
            const float sim = acc[p] * inv;
            const float u = expf(sim) / 10.0f;
            const float dcur = 1.0f / (1.0f + u);
            if (p == 0) best = dcur;
            else if (dcur > best) { best = dcur; bidx = p; }
        }

        if (sub == 0) out_min[row] = best;
        if (sub < NCLS) out_pred[(size_t)row * NCLS + sub] = lgs[bidx * NCLS + sub];

        if (it < 3) {
            #pragma unroll
            for (int j = 0; j < 12; ++j) xc[j] = xn[j];
        }
    }
}

extern "C" void kernel_launch(void* const* d_in, const int* in_sizes, int n_in,
                              void* d_out, int out_size, void* d_ws, size_t ws_size,
                              hipStream_t stream) {
    const float* x          = (const float*)d_in[0];   // [B, 768]
    const int*   role_id    = (const int*)d_in[1];     // scalar
    const float* prototypes = (const float*)d_in[2];   // [260, 768]
    const float* W          = (const float*)d_in[3];   // [13, 768]
    const float* b          = (const float*)d_in[4];   // [13]
    float* out = (float*)d_out;
    float* ws  = (float*)d_ws;

    const int B = in_sizes[0] / D;                     // 131072

    proto_prep<<<1, 256, 0, stream>>>(prototypes, role_id, W, b, ws);
    proto_main<<<B / 64, 256, 0, stream>>>(x, ws, out, out + B);
}

// Round 2
// 150.916 us; speedup vs baseline: 1.3207x; 1.3207x over previous
//
#include <hip/hip_runtime.h>
#include <math.h>

#define D 768
#define NPROTO 20
#define NCLS 13

__device__ __forceinline__ float dot4f(const float4 a, const float4 b) {
    return a.x * b.x + a.y * b.y + a.z * b.z + a.w * b.w;
}

// ws layout (floats): [0, 15360) protos_norm [20][768]; [15360, 15620) logits [20][13]

// One block per prototype. Numerics identical to the round-1 (passed) prep.
__global__ __launch_bounds__(256) void proto_prep(
    const float* __restrict__ prototypes,
    const int* __restrict__ role_id,
    const float* __restrict__ W,
    const float* __restrict__ bvec,
    float* __restrict__ ws)
{
    const int p = blockIdx.x;            // 0..19
    const int tid = threadIdx.x;
    const int wave = tid >> 6;
    const int lane = tid & 63;

    const float4* src = reinterpret_cast<const float4*>(
        prototypes + ((size_t)role_id[0] * NPROTO + p) * D);
    float4 v[3];
    #pragma unroll
    for (int j = 0; j < 3; ++j) v[j] = src[lane + 64 * j];

    float ss = 0.f;
    #pragma unroll
    for (int j = 0; j < 3; ++j) ss += dot4f(v[j], v[j]);
    #pragma unroll
    for (int s = 1; s < 64; s <<= 1) ss += __shfl_xor(ss, s, 64);
    const float nrm = fmaxf(sqrtf(ss), 1e-12f);

    float4 nv[3];
    #pragma unroll
    for (int j = 0; j < 3; ++j) {
        nv[j].x = v[j].x / nrm; nv[j].y = v[j].y / nrm;
        nv[j].z = v[j].z / nrm; nv[j].w = v[j].w / nrm;
    }
    if (wave == 0) {
        float4* dst = reinterpret_cast<float4*>(ws + (size_t)p * D);
        #pragma unroll
        for (int j = 0; j < 3; ++j) dst[lane + 64 * j] = nv[j];
    }

    // classes striped over waves: wave w does r = w, w+4, w+8, ...
    for (int r = wave; r < NCLS; r += 4) {
        const float4* wr = reinterpret_cast<const float4*>(W + (size_t)r * D);
        float a = 0.f;
        #pragma unroll
        for (int j = 0; j < 3; ++j) a += dot4f(nv[j], wr[lane + 64 * j]);
        #pragma unroll
        for (int s = 1; s < 64; s <<= 1) a += __shfl_xor(a, s, 64);
        if (lane == 0) ws[NPROTO * D + p * NCLS + r] = a + bvec[r];
    }
}

// 16 lanes per row-group, each group owns 4 rows -> each LDS proto read
// is reused for 4 rows (4x less LDS traffic than 1 row/lane).
__global__ __launch_bounds__(256, 2) void proto_main(
    const float* __restrict__ x,
    const float* __restrict__ ws,
    float* __restrict__ out_min,
    float* __restrict__ out_pred)
{
    __shared__ float pl[NPROTO * D];        // 61440 B
    __shared__ float lgs[NPROTO * NCLS];    // 1040 B
    const int tid = threadIdx.x;

    {
        const float4* src = reinterpret_cast<const float4*>(ws);
        float4* dst = reinterpret_cast<float4*>(pl);
        #pragma unroll
        for (int k = 0; k < 15; ++k) dst[tid + 256 * k] = src[tid + 256 * k];
        lgs[tid] = ws[NPROTO * D + tid];
        if (tid < NPROTO * NCLS - 256) lgs[256 + tid] = ws[NPROTO * D + 256 + tid];
    }
    __syncthreads();

    const int wave = tid >> 6;
    const int lane = tid & 63;
    const int g = lane >> 4;        // group within wave
    const int sub = lane & 15;      // chunk position within row
    const int row0 = blockIdx.x * 64 + wave * 16 + g * 4;   // this group's 4 rows
    const float* xb = x + (size_t)row0 * D;

    float acc[NPROTO][4];
    #pragma unroll
    for (int p = 0; p < NPROTO; ++p) {
        #pragma unroll
        for (int r = 0; r < 4; ++r) acc[p][r] = 0.f;
    }
    float ssx[4] = {0.f, 0.f, 0.f, 0.f};

    float4 xc[4], xn[4];
    #pragma unroll
    for (int r = 0; r < 4; ++r)
        xc[r] = reinterpret_cast<const float4*>(xb + (size_t)r * D)[sub];

    #pragma unroll
    for (int j = 0; j < 12; ++j) {
        if (j < 11) {   // prefetch next chunk while computing current
            #pragma unroll
            for (int r = 0; r < 4; ++r)
                xn[r] = reinterpret_cast<const float4*>(xb + (size_t)r * D)[sub + 16 * (j + 1)];
        }
        const float4* pr = reinterpret_cast<const float4*>(pl) + sub + 16 * j;
        #pragma unroll
        for (int p = 0; p < NPROTO; ++p) {
            const float4 pv = pr[p * (D / 4)];
            #pragma unroll
            for (int r = 0; r < 4; ++r) acc[p][r] += dot4f(xc[r], pv);
        }
        #pragma unroll
        for (int r = 0; r < 4; ++r) ssx[r] += dot4f(xc[r], xc[r]);
        if (j < 11) {
            #pragma unroll
            for (int r = 0; r < 4; ++r) xc[r] = xn[r];
        }
    }

    // reduce across the 16-lane group (xor 1,2,4,8 stays within group;
    // one instruction serves all 4 groups of the wave)
    #pragma unroll
    for (int r = 0; r < 4; ++r) {
        #pragma unroll
        for (int s = 1; s < 16; s <<= 1) ssx[r] += __shfl_xor(ssx[r], s, 64);
    }
    #pragma unroll
    for (int p = 0; p < NPROTO; ++p) {
        #pragma unroll
        for (int r = 0; r < 4; ++r) {
            #pragma unroll
            for (int s = 1; s < 16; s <<= 1) acc[p][r] += __shfl_xor(acc[p][r], s, 64);
        }
    }

    #pragma unroll
    for (int r = 0; r < 4; ++r) {
        const float inv = 1.0f / fmaxf(sqrtf(ssx[r]), 1e-12f);
        // np-order scan in dist space (strict > keeps first index on ties)
        float best = 0.f; int bidx = 0;
        #pragma unroll
        for (int p = 0; p < NPROTO; ++p) {
            const float sim = acc[p][r] * inv;
            const float u = expf(sim) / 10.0f;
            const float dcur = 1.0f / (1.0f + u);
            if (p == 0) best = dcur;
            else if (dcur > best) { best = dcur; bidx = p; }
        }
        const int row = row0 + r;
        if (sub == 0) out_min[row] = best;
        if (sub < NCLS) out_pred[(size_t)row * NCLS + sub] = lgs[bidx * NCLS + sub];
    }
}

extern "C" void kernel_launch(void* const* d_in, const int* in_sizes, int n_in,
                              void* d_out, int out_size, void* d_ws, size_t ws_size,
                              hipStream_t stream) {
    const float* x          = (const float*)d_in[0];   // [B, 768]
    const int*   role_id    = (const int*)d_in[1];     // scalar
    const float* prototypes = (const float*)d_in[2];   // [260, 768]
    const float* W          = (const float*)d_in[3];   // [13, 768]
    const float* b          = (const float*)d_in[4];   // [13]
    float* out = (float*)d_out;
    float* ws  = (float*)d_ws;

    const int B = in_sizes[0] / D;                     // 131072

    proto_prep<<<NPROTO, 256, 0, stream>>>(prototypes, role_id, W, b, ws);
    proto_main<<<B / 64, 256, 0, stream>>>(x, ws, out, out + B);
}

// Round 3
// 113.684 us; speedup vs baseline: 1.7532x; 1.3275x over previous
//
#include <hip/hip_runtime.h>
#include <math.h>

#define D 768
#define NPROTO 20
#define NCLS 13
#define D4 (D / 4)      // 192 float4 per row
#define NK (D4 / 4)     // 48 k-iterations (4 lanes/row, one float4 each)

__device__ __forceinline__ float dot4f(const float4 a, const float4 b) {
    return a.x * b.x + a.y * b.y + a.z * b.z + a.w * b.w;
}

// sum over aligned 4-lane quads via DPP quad_perm (VALU pipe, no LDS/ds_swizzle)
__device__ __forceinline__ float quad_red(float v) {
    v += __int_as_float(__builtin_amdgcn_update_dpp(
        0, __float_as_int(v), 0xB1, 0xF, 0xF, true));   // xor 1
    v += __int_as_float(__builtin_amdgcn_update_dpp(
        0, __float_as_int(v), 0x4E, 0xF, 0xF, true));   // xor 2
    return v;
}

// ws layout (floats): [0, 15360) protos_norm [20][768]; [15360, 15620) logits [20][13]

// One block per prototype. Numerics identical to the round-1/2 (passed) prep.
__global__ __launch_bounds__(256) void proto_prep(
    const float* __restrict__ prototypes,
    const int* __restrict__ role_id,
    const float* __restrict__ W,
    const float* __restrict__ bvec,
    float* __restrict__ ws)
{
    const int p = blockIdx.x;            // 0..19
    const int tid = threadIdx.x;
    const int wave = tid >> 6;
    const int lane = tid & 63;

    const float4* src = reinterpret_cast<const float4*>(
        prototypes + ((size_t)role_id[0] * NPROTO + p) * D);
    float4 v[3];
    #pragma unroll
    for (int j = 0; j < 3; ++j) v[j] = src[lane + 64 * j];

    float ss = 0.f;
    #pragma unroll
    for (int j = 0; j < 3; ++j) ss += dot4f(v[j], v[j]);
    #pragma unroll
    for (int s = 1; s < 64; s <<= 1) ss += __shfl_xor(ss, s, 64);
    const float nrm = fmaxf(sqrtf(ss), 1e-12f);

    float4 nv[3];
    #pragma unroll
    for (int j = 0; j < 3; ++j) {
        nv[j].x = v[j].x / nrm; nv[j].y = v[j].y / nrm;
        nv[j].z = v[j].z / nrm; nv[j].w = v[j].w / nrm;
    }
    if (wave == 0) {
        float4* dst = reinterpret_cast<float4*>(ws + (size_t)p * D);
        #pragma unroll
        for (int j = 0; j < 3; ++j) dst[lane + 64 * j] = nv[j];
    }

    for (int r = wave; r < NCLS; r += 4) {
        const float4* wr = reinterpret_cast<const float4*>(W + (size_t)r * D);
        float a = 0.f;
        #pragma unroll
        for (int j = 0; j < 3; ++j) a += dot4f(nv[j], wr[lane + 64 * j]);
        #pragma unroll
        for (int s = 1; s < 64; s <<= 1) a += __shfl_xor(a, s, 64);
        if (lane == 0) ws[NPROTO * D + p * NCLS + r] = a + bvec[r];
    }
}

// 4 lanes per row, 4 rows per quad -> 64 rows per wave pass, 256 per block.
// Proto LDS reads broadcast across the 16 quads; reductions are DPP-only.
__global__ __launch_bounds__(256, 2) void proto_main(
    const float* __restrict__ x,
    const float* __restrict__ ws,
    float* __restrict__ out_min,
    float* __restrict__ out_pred)
{
    __shared__ float pl[NPROTO * D];        // 61440 B
    __shared__ float lgs[NPROTO * NCLS];
    const int tid = threadIdx.x;

    {
        const float4* src = reinterpret_cast<const float4*>(ws);
        float4* dst = reinterpret_cast<float4*>(pl);
        #pragma unroll
        for (int k = 0; k < 15; ++k) dst[tid + 256 * k] = src[tid + 256 * k];
        lgs[tid] = ws[NPROTO * D + tid];
        if (tid < NPROTO * NCLS - 256) lgs[256 + tid] = ws[NPROTO * D + 256 + tid];
    }
    __syncthreads();

    const int wave = tid >> 6;
    const int lane = tid & 63;
    const int quad = lane >> 2;     // 0..15
    const int sub  = lane & 3;      // lane's float4 slot within a 4-float4 chunk
    const int row0 = blockIdx.x * 256 + wave * 64 + quad * 4;

    const float4* xr0 = reinterpret_cast<const float4*>(x + (size_t)(row0 + 0) * D) + sub;
    const float4* xr1 = reinterpret_cast<const float4*>(x + (size_t)(row0 + 1) * D) + sub;
    const float4* xr2 = reinterpret_cast<const float4*>(x + (size_t)(row0 + 2) * D) + sub;
    const float4* xr3 = reinterpret_cast<const float4*>(x + (size_t)(row0 + 3) * D) + sub;

    float acc[NPROTO][4];
    #pragma unroll
    for (int p = 0; p < NPROTO; ++p) {
        #pragma unroll
        for (int r = 0; r < 4; ++r) acc[p][r] = 0.f;
    }
    float ssx[4] = {0.f, 0.f, 0.f, 0.f};

    const float4* pl4 = reinterpret_cast<const float4*>(pl);

    float4 xa[4], xb[4];
    xa[0] = xr0[0]; xa[1] = xr1[0]; xa[2] = xr2[0]; xa[3] = xr3[0];

    for (int k = 0; k < NK; k += 2) {
        // prefetch chunk k+1 (always exists: NK even)
        xb[0] = xr0[4 * (k + 1)]; xb[1] = xr1[4 * (k + 1)];
        xb[2] = xr2[4 * (k + 1)]; xb[3] = xr3[4 * (k + 1)];

        {   // compute chunk k
            const float4* pp = pl4 + 4 * k + sub;
            #pragma unroll
            for (int p = 0; p < NPROTO; ++p) {
                const float4 pv = pp[p * D4];
                #pragma unroll
                for (int r = 0; r < 4; ++r) acc[p][r] += dot4f(xa[r], pv);
            }
            #pragma unroll
            for (int r = 0; r < 4; ++r) ssx[r] += dot4f(xa[r], xa[r]);
        }

        if (k + 2 < NK) {   // prefetch chunk k+2
            xa[0] = xr0[4 * (k + 2)]; xa[1] = xr1[4 * (k + 2)];
            xa[2] = xr2[4 * (k + 2)]; xa[3] = xr3[4 * (k + 2)];
        }

        {   // compute chunk k+1
            const float4* pp = pl4 + 4 * (k + 1) + sub;
            #pragma unroll
            for (int p = 0; p < NPROTO; ++p) {
                const float4 pv = pp[p * D4];
                #pragma unroll
                for (int r = 0; r < 4; ++r) acc[p][r] += dot4f(xb[r], pv);
            }
            #pragma unroll
            for (int r = 0; r < 4; ++r) ssx[r] += dot4f(xb[r], xb[r]);
        }
    }

    #pragma unroll
    for (int r = 0; r < 4; ++r) {
        const float ss = quad_red(ssx[r]);
        const float inv = 1.0f / fmaxf(sqrtf(ss), 1e-12f);

        // np-order scan in dist space (strict > keeps first index on ties)
        float best = 0.f; int bidx = 0;
        #pragma unroll
        for (int p = 0; p < NPROTO; ++p) {
            const float sim = quad_red(acc[p][r]) * inv;
            const float u = expf(sim) / 10.0f;
            const float dcur = 1.0f / (1.0f + u);
            if (p == 0) best = dcur;
            else if (dcur > best) { best = dcur; bidx = p; }
        }

        const int row = row0 + r;
        if (sub == 0) out_min[row] = best;
        #pragma unroll
        for (int m = 0; m < 4; ++m) {
            const int c = sub + 4 * m;
            if (c < NCLS) out_pred[(size_t)row * NCLS + c] = lgs[bidx * NCLS + c];
        }
    }
}

extern "C" void kernel_launch(void* const* d_in, const int* in_sizes, int n_in,
                              void* d_out, int out_size, void* d_ws, size_t ws_size,
                              hipStream_t stream) {
    const float* x          = (const float*)d_in[0];   // [B, 768]
    const int*   role_id    = (const int*)d_in[1];     // scalar
    const float* prototypes = (const float*)d_in[2];   // [260, 768]
    const float* W          = (const float*)d_in[3];   // [13, 768]
    const float* b          = (const float*)d_in[4];   // [13]
    float* out = (float*)d_out;
    float* ws  = (float*)d_ws;

    const int B = in_sizes[0] / D;                     // 131072

    proto_prep<<<NPROTO, 256, 0, stream>>>(prototypes, role_id, W, b, ws);
    proto_main<<<B / 256, 256, 0, stream>>>(x, ws, out, out + B);
}